// Round 15
// baseline (380.184 us; speedup 1.0000x reference)
//
#include <hip/hip_runtime.h>
#include <hip/hip_bf16.h>
#include <cstdint>
#include <cstddef>

#define B_ 2
#define T_ 2048
#define NH 16
#define NKV 4
#define DH 128
#define DM 2048
#define WIN 512
#define QKS 2560  // qkv row stride (q 2048 | k 512); v goes straight to vt

typedef __attribute__((ext_vector_type(4))) float f32x4;
typedef __attribute__((ext_vector_type(8))) __bf16 bf16x8;

using bf16 = __hip_bfloat16;

__device__ inline void gload_lds16(const void* g, void* l) {
  __builtin_amdgcn_global_load_lds(
      (const __attribute__((address_space(1))) void*)g,
      (__attribute__((address_space(3))) void*)l, 16, 0, 0);
}

__device__ inline unsigned pack_bf2(float a, float b) {
  unsigned short ua = __builtin_bit_cast(unsigned short, __float2bfloat16(a));
  unsigned short ub = __builtin_bit_cast(unsigned short, __float2bfloat16(b));
  return (unsigned)ua | ((unsigned)ub << 16);
}

#define FBAR()                           \
  do {                                   \
    asm volatile("" ::: "memory");       \
    __builtin_amdgcn_s_barrier();        \
    asm volatile("" ::: "memory");       \
  } while (0)

// ---------------- prep: x fp32->bf16 + all weight transposes ----------------
__global__ __launch_bounds__(256) void k_prep(const float* __restrict__ x,
                                              const float* __restrict__ Wq,
                                              const float* __restrict__ Wk,
                                              const float* __restrict__ Wv,
                                              const float* __restrict__ Wo,
                                              bf16* __restrict__ xb,
                                              bf16* __restrict__ Wqkvt,
                                              bf16* __restrict__ Wot) {
  int id = blockIdx.x;
  int tid = threadIdx.x;
  if (id >= 2560) {  // convert
    size_t base = (size_t)(id - 2560) * 4096 + tid * 16;
#pragma unroll
    for (int j = 0; j < 4; ++j) {
      float4 v = *(const float4*)(x + base + j * 4);
      ushort4 o;
      o.x = __builtin_bit_cast(unsigned short, __float2bfloat16(v.x));
      o.y = __builtin_bit_cast(unsigned short, __float2bfloat16(v.y));
      o.z = __builtin_bit_cast(unsigned short, __float2bfloat16(v.z));
      o.w = __builtin_bit_cast(unsigned short, __float2bfloat16(v.w));
      *(ushort4*)(xb + base + j * 4) = o;
    }
    return;
  }
  const float* W;
  bf16* Wt;
  int N, bx, by;
  if (id < 1024) { W = Wq; Wt = Wqkvt; N = 2048; bx = id & 31; by = id >> 5; }
  else if (id < 1280) { id -= 1024; W = Wk; Wt = Wqkvt + (size_t)2048 * 2048; N = 512; bx = id & 7; by = id >> 3; }
  else if (id < 1536) { id -= 1280; W = Wv; Wt = Wqkvt + (size_t)2560 * 2048; N = 512; bx = id & 7; by = id >> 3; }
  else { id -= 1536; W = Wo; Wt = Wot; N = 2048; bx = id & 31; by = id >> 5; }

  __shared__ float tile[64][65];
  int n0 = bx * 64, k0 = by * 64;
  int tx = tid & 63, tg = tid >> 6;
#pragma unroll
  for (int r = 0; r < 16; ++r) {
    int k = tg * 16 + r;
    tile[k][tx] = W[(size_t)(k0 + k) * N + n0 + tx];
  }
  __syncthreads();
#pragma unroll
  for (int r = 0; r < 16; ++r) {
    int nn = tg * 16 + r;
    Wt[(size_t)(n0 + nn) * 2048 + k0 + tx] = __float2bfloat16(tile[tx][nn]);
  }
}

// ======== 128-row single-phase GEMM, A DIRECT-FROM-GLOBAL ========
// BM=128, BN=128, BK=64, 8 waves (2M x 4N), wave tile 64x32.
// A fragments are loaded straight from global into VGPRs (double-buffered one
// K-tile ahead; rows are L1-resident across same-wm waves, xb is L2/L3-hot).
// Only B is LDS-staged (gload_lds + XOR swizzle): staged bytes/tile = 16KB ->
// FLOP/staged-byte = BM = 128 (vs 76.8 staging both). LDS 32KB, 2 blocks/CU.
// Counted vmcnt(8+NB) per body (8 A-loads + NB B-stages issued per body).
// EPI: 0 = fp32 C, 2 = fused qkv epilogue (rope q/k, v->vt^T)
template <int EPI>
__global__ __launch_bounds__(512, 4) void k_gA(const bf16* __restrict__ A,
                                               const bf16* __restrict__ Bt,
                                               void* __restrict__ Cout,
                                               int M, int N, int K,
                                               const float* __restrict__ cosT,
                                               const float* __restrict__ sinT,
                                               bf16* __restrict__ vt) {
  constexpr int NR = 2;  // n-frags per wave
  constexpr int NB = 2;  // B stage-issues per tile
  __shared__ __align__(16) char Bs_[2][16384];

  const int tid = threadIdx.x;
  const int w = tid >> 6, lane = tid & 63;
  const int li = lane & 15, g = lane >> 4;
  const int wm = w >> 2, wn = w & 3;

  const int nwg = gridDim.x * gridDim.y;
  int bid = blockIdx.y * gridDim.x + blockIdx.x;
  bid = (bid & 7) * (nwg >> 3) + (bid >> 3);
  const int m0 = (bid / gridDim.x) * 128;
  const int n0 = (bid % gridDim.x) * 128;

  const int ntiles = K >> 6;
  const int NT2 = ntiles >> 1;

  auto sB = [&](int buf, int tile, int issue) {
    const int block = issue * 8 + w;
    const int rr = block * 8 + (lane >> 3);
    const int sl = lane & 7;
    const bf16* src = Bt + (size_t)(n0 + rr) * K + tile * 64 + ((sl ^ (rr & 7)) * 8);
    gload_lds16(src, Bs_[buf] + block * 1024);
  };

  const int swz0 = (g ^ (li & 7)) * 16;
  const int swz1 = ((4 + g) ^ (li & 7)) * 16;
  bf16x8 afA[8], afB[8], bv[NR * 2];
  f32x4 acc[4][NR] = {};

  // A-frag base: rows m0 + wm*64 + mf*16 + li, k = tile*64 + kk*32 + g*8
  const bf16* aBase = A + (size_t)(m0 + wm * 64 + li) * K + g * 8;

  auto loadA = [&](bf16x8* af, int tile) {
#pragma unroll
    for (int mf = 0; mf < 4; ++mf)
#pragma unroll
      for (int kk = 0; kk < 2; ++kk)
        af[mf * 2 + kk] =
            *(const bf16x8*)(aBase + (size_t)(mf * 16) * K + tile * 64 + kk * 32);
  };
  auto readB = [&](int buf) {
#pragma unroll
    for (int n = 0; n < NR; ++n) {
      const char* p = Bs_[buf] + (wn * (NR * 16) + n * 16 + li) * 128;
      bv[n * 2 + 0] = *(const bf16x8*)(p + swz0);
      bv[n * 2 + 1] = *(const bf16x8*)(p + swz1);
    }
  };
  auto MMA = [&](const bf16x8* af) {
    __builtin_amdgcn_s_setprio(1);
#pragma unroll
    for (int mf = 0; mf < 4; ++mf)
#pragma unroll
      for (int n = 0; n < NR; ++n)
#pragma unroll
        for (int kk = 0; kk < 2; ++kk)
          acc[mf][n] = __builtin_amdgcn_mfma_f32_16x16x32_bf16(
              af[mf * 2 + kk], bv[n * 2 + kk], acc[mf][n], 0, 0, 0);
    __builtin_amdgcn_s_setprio(0);
  };

  // ---- prologue: A(0) -> afA, stage B(0) -> buf0 ----
  loadA(afA, 0);
  sB(0, 0, 0); sB(0, 0, 1);

  for (int itr = 0; itr < NT2; ++itr) {
    {  // body even: tile t = 2*itr, buf0, cur=afA, next=afB
      const int t = itr * 2;
      const bool more = (t + 1 < ntiles);
      if (more) {
        loadA(afB, t + 1);
        sB(1, t + 1, 0); sB(1, t + 1, 1);
      }
      if (more)
        asm volatile("s_waitcnt vmcnt(10)" ::: "memory");
      else
        asm volatile("s_waitcnt vmcnt(0)" ::: "memory");
      __builtin_amdgcn_sched_barrier(0);
      FBAR();
      readB(0);
      MMA(afA);
      FBAR();
    }
    {  // body odd: tile t = 2*itr+1, buf1, cur=afB, next=afA
      const int t = itr * 2 + 1;
      const bool more = (t + 1 < ntiles);
      if (more) {
        loadA(afA, t + 1);
        sB(0, t + 1, 0); sB(0, t + 1, 1);
      }
      if (more)
        asm volatile("s_waitcnt vmcnt(10)" ::: "memory");
      else
        asm volatile("s_waitcnt vmcnt(0)" ::: "memory");
      __builtin_amdgcn_sched_barrier(0);
      FBAR();
      readB(1);
      MMA(afB);
      FBAR();
    }
  }

  // ---------------- epilogue ----------------
#pragma unroll
  for (int mf = 0; mf < 4; ++mf)
#pragma unroll
    for (int nf = 0; nf < NR; ++nf) {
      const int colc = n0 + wn * (NR * 16) + nf * 16;  // wave-uniform
      const int col = colc + li;
      const int row0 = m0 + wm * 64 + mf * 16 + g * 4;
      if constexpr (EPI == 2) {
        if (colc < QKS) {  // q or k: rope (q additionally pre-scaled)
          const float qs = (colc < 2048) ? 0.08838834764831845f : 1.0f;
          const int i = (col & 127) >> 1;
          const float sgn = (li & 1) ? 1.0f : -1.0f;
#pragma unroll
          for (int r = 0; r < 4; ++r) {
            const int trow = (row0 + r) & (T_ - 1);
            float v = acc[mf][nf][r];
            float pv = __shfl_xor(v, 1);
            float c = cosT[trow * 64 + i], s = sinT[trow * 64 + i];
            float o = (v * c + pv * (sgn * s)) * qs;
            ((bf16*)Cout)[(size_t)(row0 + r) * QKS + col] = __float2bfloat16(o);
          }
        } else {  // v: write transposed into vt[col-2560][row], 4 rows packed
          unsigned lo = pack_bf2(acc[mf][nf][0], acc[mf][nf][1]);
          unsigned hi = pack_bf2(acc[mf][nf][2], acc[mf][nf][3]);
          uint2 pk = {lo, hi};
          *(uint2*)(vt + (size_t)(col - QKS) * (B_ * T_) + row0) = pk;
        }
      } else {
#pragma unroll
        for (int r = 0; r < 4; ++r)
          ((float*)Cout)[(size_t)(row0 + r) * N + col] = acc[mf][nf][r];
      }
    }
}

// ---------------- windowed flash attention, swapped QK^T (R7 config) -------
__global__ __launch_bounds__(512) void k_attn(const bf16* __restrict__ qkv,
                                              const bf16* __restrict__ vt,
                                              bf16* __restrict__ Y) {
  __shared__ __align__(16) char Ks[2][9216];
  __shared__ __align__(16) char Vs[2][10240];
  __shared__ __align__(16) char Pl[8][1280];
  const int lane = threadIdx.x & 63;
  const int w = threadIdx.x >> 6;
  const int li = lane & 15, g = lane >> 4;
  const int t0 = ((int)gridDim.x - 1 - (int)blockIdx.x) * 32;
  const int b = blockIdx.y / NKV, kvh = blockIdx.y % NKV;
  const int h = kvh * 4 + (w >> 1);
  const int qrow0 = t0 + (w & 1) * 16;
  const int t = qrow0 + li;

  bf16x8 qf[4];
  const bf16* qbase = qkv + (size_t)(b * T_ + qrow0 + li) * QKS + h * DH;
#pragma unroll
  for (int dk = 0; dk < 4; ++dk) qf[dk] = *(const bf16x8*)(qbase + dk * 32 + g * 8);

  float mrow = -1e4f;
  float srow = 0.f;
  f32x4 acc[8] = {};

  int ks0 = t0 - (WIN - 1);
  if (ks0 < 0) ks0 = 0;
  ks0 &= ~31;
  const int nt = (t0 + 31 - ks0) / 32 + 1;

  const bf16* kgbase = qkv + (size_t)(b * T_) * QKS + DM + kvh * DH;
  const bf16* vgbase = vt + (size_t)(kvh * DH) * (B_ * T_) + b * T_;

  auto STAGE = [&](int buf, int kt) {
    for (int c = w; c < 19; c += 8) {
      if (c < 9) {
        int slot = c * 64 + lane;
        int row = slot / 17, cc = slot % 17;
        if (slot >= 544) { row = 0; cc = 0; }
        if (cc == 16) cc = 0;
        const bf16* src = kgbase + (size_t)(kt + row) * QKS + cc * 8;
        gload_lds16(src, Ks[buf] + c * 1024);
      } else {
        int c2 = c - 9;
        int slot = c2 * 64 + lane;
        int row = slot / 5, cc = slot % 5;
        if (cc == 4) cc = 0;
        const bf16* src = vgbase + (size_t)row * (B_ * T_) + kt + cc * 8;
        gload_lds16(src, Vs[buf] + c2 * 1024);
      }
    }
  };

  STAGE(0, ks0);
  __syncthreads();
  int cur = 0;

  for (int it = 0; it < nt; ++it) {
    const int kt = ks0 + it * 32;
    if (it + 1 < nt) STAGE(cur ^ 1, kt + 32);

    f32x4 sc[2] = {};
#pragma unroll
    for (int n = 0; n < 2; ++n)
#pragma unroll
      for (int dk = 0; dk < 4; ++dk) {
        bf16x8 kf = *(const bf16x8*)(Ks[cur] + (n * 16 + li) * 272 + dk * 64 + g * 16);
        sc[n] = __builtin_amdgcn_mfma_f32_16x16x32_bf16(kf, qf[dk], sc[n], 0, 0, 0);
      }

    float p[2][4];
    float pmax = -1e30f;
#pragma unroll
    for (int n = 0; n < 2; ++n)
#pragma unroll
      for (int r = 0; r < 4; ++r) {
        int key = kt + n * 16 + g * 4 + r;
        bool valid = (key <= t) && (key > t - WIN);
        float pv = valid ? sc[n][r] : -1e30f;
        p[n][r] = pv;
        pmax = fmaxf(pmax, pv);
      }
    pmax = fmaxf(pmax, __shfl_xor(pmax, 16));
    pmax = fmaxf(pmax, __shfl_xor(pmax, 32));

    if (!__all(pmax <= mrow)) {  // T13 defer-rescale
      float nm = fmaxf(mrow, pmax);
      float alpha = __expf(mrow - nm);
      mrow = nm;
      srow *= alpha;
      float af_[4];
#pragma unroll
      for (int r = 0; r < 4; ++r) af_[r] = __shfl(alpha, (g << 2) + r);
#pragma unroll
      for (int db = 0; db < 8; ++db)
#pragma unroll
        for (int r = 0; r < 4; ++r) acc[db][r] *= af_[r];
    }

    float rs = 0.f;
#pragma unroll
    for (int n = 0; n < 2; ++n)
#pragma unroll
      for (int r = 0; r < 4; ++r) {
        p[n][r] = __expf(p[n][r] - mrow);
        rs += p[n][r];
      }
    rs += __shfl_xor(rs, 16);
    rs += __shfl_xor(rs, 32);
    srow += rs;

#pragma unroll
    for (int n = 0; n < 2; ++n) {
      *(unsigned*)(Pl[w] + li * 80 + n * 32 + g * 8) = pack_bf2(p[n][0], p[n][1]);
      *(unsigned*)(Pl[w] + li * 80 + n * 32 + g * 8 + 4) = pack_bf2(p[n][2], p[n][3]);
    }

    bf16x8 pf = *(const bf16x8*)(Pl[w] + li * 80 + g * 16);
#pragma unroll
    for (int db = 0; db < 8; ++db) {
      bf16x8 vf = *(const bf16x8*)(Vs[cur] + (db * 16 + li) * 80 + g * 16);
      acc[db] = __builtin_amdgcn_mfma_f32_16x16x32_bf16(pf, vf, acc[db], 0, 0, 0);
    }

    __syncthreads();
    cur ^= 1;
  }

  float inv[4];
#pragma unroll
  for (int r = 0; r < 4; ++r) inv[r] = 1.f / __shfl(srow, (g << 2) + r);
  bf16* ybase = Y + (size_t)(b * T_ + qrow0 + (g << 2)) * DM + h * DH;
#pragma unroll
  for (int r = 0; r < 4; ++r)
#pragma unroll
    for (int db = 0; db < 8; ++db)
      ybase[(size_t)r * DM + db * 16 + li] = __float2bfloat16(acc[db][r] * inv[r]);
}

extern "C" void kernel_launch(void* const* d_in, const int* in_sizes, int n_in,
                              void* d_out, int out_size, void* d_ws, size_t ws_size,
                              hipStream_t stream) {
  const float* x = (const float*)d_in[0];
  const float* cosT = (const float*)d_in[1];
  const float* sinT = (const float*)d_in[2];
  const float* Wq = (const float*)d_in[3];
  const float* Wk = (const float*)d_in[4];
  const float* Wv = (const float*)d_in[5];
  const float* Wo = (const float*)d_in[6];
  float* out = (float*)d_out;

  char* ws = (char*)d_ws;
  bf16* xb = (bf16*)ws;     ws += (size_t)4096 * 2048 * 2;   // 16.8 MB (reused as yb)
  bf16* Wqkvt = (bf16*)ws;  ws += (size_t)3072 * 2048 * 2;   // 12.6 MB
  bf16* Wot = (bf16*)ws;    ws += (size_t)2048 * 2048 * 2;   // 8.4 MB
  bf16* qkv = (bf16*)ws;    ws += (size_t)4096 * QKS * 2;    // 21.0 MB (q|k only)
  bf16* vt = (bf16*)ws;     ws += (size_t)512 * 4096 * 2;    // 4.2 MB (V^T)
  bf16* yb = xb;

  k_prep<<<4608, 256, 0, stream>>>(x, Wq, Wk, Wv, Wo, xb, Wqkvt, Wot);

  k_gA<2><<<dim3(3072 / 128, 4096 / 128), 512, 0, stream>>>(
      xb, Wqkvt, qkv, 4096, 3072, 2048, cosT, sinT, vt);

  k_attn<<<dim3(T_ / 32, B_ * NKV), 512, 0, stream>>>(qkv, vt, yb);

  k_gA<0><<<dim3(2048 / 128, 4096 / 128), 512, 0, stream>>>(
      yb, Wot, out, 4096, 2048, 2048, nullptr, nullptr, nullptr);
}

// Round 16
// 156.360 us; speedup vs baseline: 2.4315x; 2.4315x over previous
//
#include <hip/hip_runtime.h>
#include <hip/hip_bf16.h>
#include <cstdint>
#include <cstddef>

#define B_ 2
#define T_ 2048
#define NH 16
#define NKV 4
#define DH 128
#define DM 2048
#define WIN 512
#define QKS 2560  // qkv row stride (q 2048 | k 512); v goes straight to vt

typedef __attribute__((ext_vector_type(4))) float f32x4;
typedef __attribute__((ext_vector_type(8))) __bf16 bf16x8;

using bf16 = __hip_bfloat16;

__device__ inline void gload_lds16(const void* g, void* l) {
  __builtin_amdgcn_global_load_lds(
      (const __attribute__((address_space(1))) void*)g,
      (__attribute__((address_space(3))) void*)l, 16, 0, 0);
}

__device__ inline unsigned pack_bf2(float a, float b) {
  unsigned short ua = __builtin_bit_cast(unsigned short, __float2bfloat16(a));
  unsigned short ub = __builtin_bit_cast(unsigned short, __float2bfloat16(b));
  return (unsigned)ua | ((unsigned)ub << 16);
}

#define FBAR()                           \
  do {                                   \
    asm volatile("" ::: "memory");       \
    __builtin_amdgcn_s_barrier();        \
    asm volatile("" ::: "memory");       \
  } while (0)

// ---------------- prep: x fp32->bf16 + all weight transposes ----------------
__global__ __launch_bounds__(256) void k_prep(const float* __restrict__ x,
                                              const float* __restrict__ Wq,
                                              const float* __restrict__ Wk,
                                              const float* __restrict__ Wv,
                                              const float* __restrict__ Wo,
                                              bf16* __restrict__ xb,
                                              bf16* __restrict__ Wqkvt,
                                              bf16* __restrict__ Wot) {
  int id = blockIdx.x;
  int tid = threadIdx.x;
  if (id >= 2560) {  // convert
    size_t base = (size_t)(id - 2560) * 4096 + tid * 16;
#pragma unroll
    for (int j = 0; j < 4; ++j) {
      float4 v = *(const float4*)(x + base + j * 4);
      ushort4 o;
      o.x = __builtin_bit_cast(unsigned short, __float2bfloat16(v.x));
      o.y = __builtin_bit_cast(unsigned short, __float2bfloat16(v.y));
      o.z = __builtin_bit_cast(unsigned short, __float2bfloat16(v.z));
      o.w = __builtin_bit_cast(unsigned short, __float2bfloat16(v.w));
      *(ushort4*)(xb + base + j * 4) = o;
    }
    return;
  }
  const float* W;
  bf16* Wt;
  int N, bx, by;
  if (id < 1024) { W = Wq; Wt = Wqkvt; N = 2048; bx = id & 31; by = id >> 5; }
  else if (id < 1280) { id -= 1024; W = Wk; Wt = Wqkvt + (size_t)2048 * 2048; N = 512; bx = id & 7; by = id >> 3; }
  else if (id < 1536) { id -= 1280; W = Wv; Wt = Wqkvt + (size_t)2560 * 2048; N = 512; bx = id & 7; by = id >> 3; }
  else { id -= 1536; W = Wo; Wt = Wot; N = 2048; bx = id & 31; by = id >> 5; }

  __shared__ float tile[64][65];
  int n0 = bx * 64, k0 = by * 64;
  int tx = tid & 63, tg = tid >> 6;
#pragma unroll
  for (int r = 0; r < 16; ++r) {
    int k = tg * 16 + r;
    tile[k][tx] = W[(size_t)(k0 + k) * N + n0 + tx];
  }
  __syncthreads();
#pragma unroll
  for (int r = 0; r < 16; ++r) {
    int nn = tg * 16 + r;
    Wt[(size_t)(n0 + nn) * 2048 + k0 + tx] = __float2bfloat16(tile[tx][nn]);
  }
}

// ======== 128-row SINGLE-phase/K-tile MFMA GEMM, 2 blocks/CU (R12) ========
// BM=128, BK=64, 8 waves (2M x 4N), wave tile 64 x (BN/4).
// Per K-tile: {stage full next tile -> vmcnt(2+NB) -> bar -> ds_reads + 24
// MFMA (compiler interleaves lgkmcnt) -> bar}. 2 blocks/CU cover the
// stage/barrier segment. LDS: (16 + BN/64*8)KB x2 -> 80KB @192, 64KB @128.
// R15 change: COLUMN-major bid decomposition (m0 fastest within an XCD
// chunk) so co-XCD blocks share the B panel (<1MB, fits 4MB XCD L2).
// EPI: 0 = fp32 C, 2 = fused qkv epilogue (rope q/k, v->vt^T)
template <int BN, int EPI>
__global__ __launch_bounds__(512, 4) void k_gemm1(const bf16* __restrict__ A,
                                                  const bf16* __restrict__ Bt,
                                                  void* __restrict__ Cout,
                                                  int M, int N, int K,
                                                  const float* __restrict__ cosT,
                                                  const float* __restrict__ sinT,
                                                  bf16* __restrict__ vt) {
  constexpr int NR = BN / 64;          // n-frags per wave (3 or 2)
  constexpr int NB = BN * 128 / 8192;  // B stage-issues per tile (3 or 2)
  __shared__ __align__(16) char As_[2][16384];
  __shared__ __align__(16) char Bs_[2][BN * 128];

  const int tid = threadIdx.x;
  const int w = tid >> 6, lane = tid & 63;
  const int li = lane & 15, g = lane >> 4;
  const int wm = w >> 2, wn = w & 3;

  const int nwg = gridDim.x * gridDim.y;
  int bid = blockIdx.y * gridDim.x + blockIdx.x;
  bid = (bid & 7) * (nwg >> 3) + (bid >> 3);
  // column-major: m0 varies fastest -> consecutive co-XCD blocks share n0/B
  const int m0 = (bid % gridDim.y) * 128;
  const int n0 = (bid / gridDim.y) * BN;

  const int ntiles = K >> 6;

  // A half h = rows with bit5==h; within half, rl = (row&31) + 32*(row>>6)
  auto sA = [&](int buf, int tile, int h) {
    if (tile >= ntiles) return;
    const int rl = tid >> 3;              // 0..63
    const int row = (rl & 31) + h * 32 + ((rl >> 5) << 6);
    const int sl = tid & 7;
    const bf16* src = A + (size_t)(m0 + row) * K + tile * 64 + ((sl ^ (rl & 7)) * 8);
    gload_lds16(src, As_[buf] + h * 8192 + tid * 16);
  };
  auto sB = [&](int buf, int tile, int issue) {
    if (tile >= ntiles) return;
    const int block = issue * 8 + w;
    const int rr = block * 8 + (lane >> 3);
    const int sl = lane & 7;
    const bf16* src = Bt + (size_t)(n0 + rr) * K + tile * 64 + ((sl ^ (rr & 7)) * 8);
    gload_lds16(src, Bs_[buf] + block * 1024);
  };

  const int swz0 = (g ^ (li & 7)) * 16;
  const int swz1 = ((4 + g) ^ (li & 7)) * 16;
  bf16x8 af[8], bv[NR * 2];
  f32x4 acc[4][NR] = {};

  auto readA = [&](int buf) {  // 4 m-frags; frag mf row-base = wm*64 + mf*16
#pragma unroll
    for (int mf = 0; mf < 4; ++mf) {
      const int h = (mf >> 1) & 1;
      const int rl = (mf & 1) * 16 + li + 32 * wm;
      const char* p = As_[buf] + h * 8192 + rl * 128;
      af[mf * 2 + 0] = *(const bf16x8*)(p + swz0);
      af[mf * 2 + 1] = *(const bf16x8*)(p + swz1);
    }
  };
  auto readB = [&](int buf) {
#pragma unroll
    for (int n = 0; n < NR; ++n) {
      const char* p = Bs_[buf] + (wn * (NR * 16) + n * 16 + li) * 128;
      bv[n * 2 + 0] = *(const bf16x8*)(p + swz0);
      bv[n * 2 + 1] = *(const bf16x8*)(p + swz1);
    }
  };
  auto MMA = [&]() {
    __builtin_amdgcn_s_setprio(1);
#pragma unroll
    for (int mf = 0; mf < 4; ++mf)
#pragma unroll
      for (int n = 0; n < NR; ++n)
#pragma unroll
        for (int kk = 0; kk < 2; ++kk)
          acc[mf][n] = __builtin_amdgcn_mfma_f32_16x16x32_bf16(
              af[mf * 2 + kk], bv[n * 2 + kk], acc[mf][n], 0, 0, 0);
    __builtin_amdgcn_s_setprio(0);
  };

  // ---- prologue: stage tile0 (2+NB issues) ----
  sA(0, 0, 0); sA(0, 0, 1);
#pragma unroll
  for (int i = 0; i < NB; ++i) sB(0, 0, i);

  for (int t = 0; t < ntiles; ++t) {
    const int cb = t & 1;
    const bool last = (t == ntiles - 1);
    // stage full next tile into the other buffer (its last reads finished
    // before the previous iteration's trailing barrier)
    sA(cb ^ 1, t + 1, 0); sA(cb ^ 1, t + 1, 1);
#pragma unroll
    for (int i = 0; i < NB; ++i) sB(cb ^ 1, t + 1, i);
    // retire everything except this iteration's (2+NB) issues -> tile t ready
    if (last)
      asm volatile("s_waitcnt vmcnt(0)" ::: "memory");
    else if constexpr (NB == 3)
      asm volatile("s_waitcnt vmcnt(5)" ::: "memory");
    else
      asm volatile("s_waitcnt vmcnt(4)" ::: "memory");
    __builtin_amdgcn_sched_barrier(0);
    FBAR();
    readA(cb); readB(cb);
    MMA();
    FBAR();
  }

  // ---------------- epilogue ----------------
#pragma unroll
  for (int mf = 0; mf < 4; ++mf)
#pragma unroll
    for (int nf = 0; nf < NR; ++nf) {
      const int colc = n0 + wn * (NR * 16) + nf * 16;  // wave-uniform
      const int col = colc + li;
      const int row0 = m0 + wm * 64 + mf * 16 + g * 4;
      if constexpr (EPI == 2) {
        if (colc < QKS) {  // q or k: rope (q additionally pre-scaled)
          const float qs = (colc < 2048) ? 0.08838834764831845f : 1.0f;
          const int i = (col & 127) >> 1;
          const float sgn = (li & 1) ? 1.0f : -1.0f;
#pragma unroll
          for (int r = 0; r < 4; ++r) {
            const int trow = (row0 + r) & (T_ - 1);
            float v = acc[mf][nf][r];
            float pv = __shfl_xor(v, 1);
            float c = cosT[trow * 64 + i], s = sinT[trow * 64 + i];
            float o = (v * c + pv * (sgn * s)) * qs;
            ((bf16*)Cout)[(size_t)(row0 + r) * QKS + col] = __float2bfloat16(o);
          }
        } else {  // v: write transposed into vt[col-2560][row], 4 rows packed
          unsigned lo = pack_bf2(acc[mf][nf][0], acc[mf][nf][1]);
          unsigned hi = pack_bf2(acc[mf][nf][2], acc[mf][nf][3]);
          uint2 pk = {lo, hi};
          *(uint2*)(vt + (size_t)(col - QKS) * (B_ * T_) + row0) = pk;
        }
      } else {
#pragma unroll
        for (int r = 0; r < 4; ++r)
          ((float*)Cout)[(size_t)(row0 + r) * N + col] = acc[mf][nf][r];
      }
    }
}

// ---------------- windowed flash attention, swapped QK^T (R7 config) -------
// grid: (T/32 [reversed], B*NKV), block 512 = 8 waves.
// wave w: head kvh*4 + (w>>1), q rows t0 + (w&1)*16 .. +15. LDS 48KB: 3/CU.
__global__ __launch_bounds__(512) void k_attn(const bf16* __restrict__ qkv,
                                              const bf16* __restrict__ vt,
                                              bf16* __restrict__ Y) {
  __shared__ __align__(16) char Ks[2][9216];
  __shared__ __align__(16) char Vs[2][10240];
  __shared__ __align__(16) char Pl[8][1280];
  const int lane = threadIdx.x & 63;
  const int w = threadIdx.x >> 6;
  const int li = lane & 15, g = lane >> 4;
  const int t0 = ((int)gridDim.x - 1 - (int)blockIdx.x) * 32;
  const int b = blockIdx.y / NKV, kvh = blockIdx.y % NKV;
  const int h = kvh * 4 + (w >> 1);
  const int qrow0 = t0 + (w & 1) * 16;
  const int t = qrow0 + li;

  bf16x8 qf[4];
  const bf16* qbase = qkv + (size_t)(b * T_ + qrow0 + li) * QKS + h * DH;
#pragma unroll
  for (int dk = 0; dk < 4; ++dk) qf[dk] = *(const bf16x8*)(qbase + dk * 32 + g * 8);

  float mrow = -1e4f;
  float srow = 0.f;
  f32x4 acc[8] = {};

  int ks0 = t0 - (WIN - 1);
  if (ks0 < 0) ks0 = 0;
  ks0 &= ~31;
  const int nt = (t0 + 31 - ks0) / 32 + 1;

  const bf16* kgbase = qkv + (size_t)(b * T_) * QKS + DM + kvh * DH;
  const bf16* vgbase = vt + (size_t)(kvh * DH) * (B_ * T_) + b * T_;

  auto STAGE = [&](int buf, int kt) {
    for (int c = w; c < 19; c += 8) {
      if (c < 9) {
        int slot = c * 64 + lane;
        int row = slot / 17, cc = slot % 17;
        if (slot >= 544) { row = 0; cc = 0; }
        if (cc == 16) cc = 0;
        const bf16* src = kgbase + (size_t)(kt + row) * QKS + cc * 8;
        gload_lds16(src, Ks[buf] + c * 1024);
      } else {
        int c2 = c - 9;
        int slot = c2 * 64 + lane;
        int row = slot / 5, cc = slot % 5;
        if (cc == 4) cc = 0;
        const bf16* src = vgbase + (size_t)row * (B_ * T_) + kt + cc * 8;
        gload_lds16(src, Vs[buf] + c2 * 1024);
      }
    }
  };

  STAGE(0, ks0);
  __syncthreads();
  int cur = 0;

  for (int it = 0; it < nt; ++it) {
    const int kt = ks0 + it * 32;
    if (it + 1 < nt) STAGE(cur ^ 1, kt + 32);

    f32x4 sc[2] = {};
#pragma unroll
    for (int n = 0; n < 2; ++n)
#pragma unroll
      for (int dk = 0; dk < 4; ++dk) {
        bf16x8 kf = *(const bf16x8*)(Ks[cur] + (n * 16 + li) * 272 + dk * 64 + g * 16);
        sc[n] = __builtin_amdgcn_mfma_f32_16x16x32_bf16(kf, qf[dk], sc[n], 0, 0, 0);
      }

    float p[2][4];
    float pmax = -1e30f;
#pragma unroll
    for (int n = 0; n < 2; ++n)
#pragma unroll
      for (int r = 0; r < 4; ++r) {
        int key = kt + n * 16 + g * 4 + r;
        bool valid = (key <= t) && (key > t - WIN);
        float pv = valid ? sc[n][r] : -1e30f;
        p[n][r] = pv;
        pmax = fmaxf(pmax, pv);
      }
    pmax = fmaxf(pmax, __shfl_xor(pmax, 16));
    pmax = fmaxf(pmax, __shfl_xor(pmax, 32));

    // T13 defer-rescale: only rescale when the running max actually grows
    if (!__all(pmax <= mrow)) {
      float nm = fmaxf(mrow, pmax);
      float alpha = __expf(mrow - nm);
      mrow = nm;
      srow *= alpha;
      float af_[4];
#pragma unroll
      for (int r = 0; r < 4; ++r) af_[r] = __shfl(alpha, (g << 2) + r);
#pragma unroll
      for (int db = 0; db < 8; ++db)
#pragma unroll
        for (int r = 0; r < 4; ++r) acc[db][r] *= af_[r];
    }

    float rs = 0.f;
#pragma unroll
    for (int n = 0; n < 2; ++n)
#pragma unroll
      for (int r = 0; r < 4; ++r) {
        p[n][r] = __expf(p[n][r] - mrow);
        rs += p[n][r];
      }
    rs += __shfl_xor(rs, 16);
    rs += __shfl_xor(rs, 32);
    srow += rs;

#pragma unroll
    for (int n = 0; n < 2; ++n) {
      *(unsigned*)(Pl[w] + li * 80 + n * 32 + g * 8) = pack_bf2(p[n][0], p[n][1]);
      *(unsigned*)(Pl[w] + li * 80 + n * 32 + g * 8 + 4) = pack_bf2(p[n][2], p[n][3]);
    }

    bf16x8 pf = *(const bf16x8*)(Pl[w] + li * 80 + g * 16);
#pragma unroll
    for (int db = 0; db < 8; ++db) {
      bf16x8 vf = *(const bf16x8*)(Vs[cur] + (db * 16 + li) * 80 + g * 16);
      acc[db] = __builtin_amdgcn_mfma_f32_16x16x32_bf16(pf, vf, acc[db], 0, 0, 0);
    }

    __syncthreads();
    cur ^= 1;
  }

  float inv[4];
#pragma unroll
  for (int r = 0; r < 4; ++r) inv[r] = 1.f / __shfl(srow, (g << 2) + r);
  bf16* ybase = Y + (size_t)(b * T_ + qrow0 + (g << 2)) * DM + h * DH;
#pragma unroll
  for (int r = 0; r < 4; ++r)
#pragma unroll
    for (int db = 0; db < 8; ++db)
      ybase[(size_t)r * DM + db * 16 + li] = __float2bfloat16(acc[db][r] * inv[r]);
}

extern "C" void kernel_launch(void* const* d_in, const int* in_sizes, int n_in,
                              void* d_out, int out_size, void* d_ws, size_t ws_size,
                              hipStream_t stream) {
  const float* x = (const float*)d_in[0];
  const float* cosT = (const float*)d_in[1];
  const float* sinT = (const float*)d_in[2];
  const float* Wq = (const float*)d_in[3];
  const float* Wk = (const float*)d_in[4];
  const float* Wv = (const float*)d_in[5];
  const float* Wo = (const float*)d_in[6];
  float* out = (float*)d_out;

  char* ws = (char*)d_ws;
  bf16* xb = (bf16*)ws;     ws += (size_t)4096 * 2048 * 2;   // 16.8 MB (reused as yb)
  bf16* Wqkvt = (bf16*)ws;  ws += (size_t)3072 * 2048 * 2;   // 12.6 MB
  bf16* Wot = (bf16*)ws;    ws += (size_t)2048 * 2048 * 2;   // 8.4 MB
  bf16* qkv = (bf16*)ws;    ws += (size_t)4096 * QKS * 2;    // 21.0 MB (q|k only)
  bf16* vt = (bf16*)ws;     ws += (size_t)512 * 4096 * 2;    // 4.2 MB (V^T)
  bf16* yb = xb;

  k_prep<<<4608, 256, 0, stream>>>(x, Wq, Wk, Wv, Wo, xb, Wqkvt, Wot);

  k_gemm1<192, 2><<<dim3(3072 / 192, 4096 / 128), 512, 0, stream>>>(
      xb, Wqkvt, qkv, 4096, 3072, 2048, cosT, sinT, vt);

  k_attn<<<dim3(T_ / 32, B_ * NKV), 512, 0, stream>>>(qkv, vt, yb);

  k_gemm1<128, 0><<<dim3(2048 / 128, 4096 / 128), 512, 0, stream>>>(
      yb, Wot, out, 4096, 2048, 2048, nullptr, nullptr, nullptr);
}

// Round 17
// 154.862 us; speedup vs baseline: 2.4550x; 1.0097x over previous
//
#include <hip/hip_runtime.h>
#include <hip/hip_bf16.h>
#include <cstdint>
#include <cstddef>

#define B_ 2
#define T_ 2048
#define NH 16
#define NKV 4
#define DH 128
#define DM 2048
#define WIN 512
#define QKS 2560  // qkv row stride (q 2048 | k 512); v goes straight to vt

typedef __attribute__((ext_vector_type(4))) float f32x4;
typedef __attribute__((ext_vector_type(8))) __bf16 bf16x8;

using bf16 = __hip_bfloat16;

__device__ inline void gload_lds16(const void* g, void* l) {
  __builtin_amdgcn_global_load_lds(
      (const __attribute__((address_space(1))) void*)g,
      (__attribute__((address_space(3))) void*)l, 16, 0, 0);
}

__device__ inline unsigned pack_bf2(float a, float b) {
  unsigned short ua = __builtin_bit_cast(unsigned short, __float2bfloat16(a));
  unsigned short ub = __builtin_bit_cast(unsigned short, __float2bfloat16(b));
  return (unsigned)ua | ((unsigned)ub << 16);
}

#define FBAR()                           \
  do {                                   \
    asm volatile("" ::: "memory");       \
    __builtin_amdgcn_s_barrier();        \
    asm volatile("" ::: "memory");       \
  } while (0)

// ---------------- prep: x fp32->bf16 + all weight transposes ----------------
// Transpose: float2 loads (8B/lane), packed-u32 bf16 stores (4B/lane).
__global__ __launch_bounds__(256) void k_prep(const float* __restrict__ x,
                                              const float* __restrict__ Wq,
                                              const float* __restrict__ Wk,
                                              const float* __restrict__ Wv,
                                              const float* __restrict__ Wo,
                                              bf16* __restrict__ xb,
                                              bf16* __restrict__ Wqkvt,
                                              bf16* __restrict__ Wot) {
  int id = blockIdx.x;
  int tid = threadIdx.x;
  if (id >= 2560) {  // convert
    size_t base = (size_t)(id - 2560) * 4096 + tid * 16;
#pragma unroll
    for (int j = 0; j < 4; ++j) {
      float4 v = *(const float4*)(x + base + j * 4);
      ushort4 o;
      o.x = __builtin_bit_cast(unsigned short, __float2bfloat16(v.x));
      o.y = __builtin_bit_cast(unsigned short, __float2bfloat16(v.y));
      o.z = __builtin_bit_cast(unsigned short, __float2bfloat16(v.z));
      o.w = __builtin_bit_cast(unsigned short, __float2bfloat16(v.w));
      *(ushort4*)(xb + base + j * 4) = o;
    }
    return;
  }
  const float* W;
  bf16* Wt;
  int N, bx, by;
  if (id < 1024) { W = Wq; Wt = Wqkvt; N = 2048; bx = id & 31; by = id >> 5; }
  else if (id < 1280) { id -= 1024; W = Wk; Wt = Wqkvt + (size_t)2048 * 2048; N = 512; bx = id & 7; by = id >> 3; }
  else if (id < 1536) { id -= 1280; W = Wv; Wt = Wqkvt + (size_t)2560 * 2048; N = 512; bx = id & 7; by = id >> 3; }
  else { id -= 1536; W = Wo; Wt = Wot; N = 2048; bx = id & 31; by = id >> 5; }

  __shared__ float tile[64][65];
  const int n0 = bx * 64, k0 = by * 64;
  const int c2 = tid & 31;  // col-pair (load) / k-pair (store)
  const int rg = tid >> 5;  // 0..7
#pragma unroll
  for (int r = 0; r < 8; ++r) {
    int k = r * 8 + rg;
    float2 v = *(const float2*)&W[(size_t)(k0 + k) * N + n0 + c2 * 2];
    tile[k][c2 * 2] = v.x;
    tile[k][c2 * 2 + 1] = v.y;
  }
  __syncthreads();
#pragma unroll
  for (int r = 0; r < 8; ++r) {
    int nn = r * 8 + rg;
    unsigned pk = pack_bf2(tile[c2 * 2][nn], tile[c2 * 2 + 1][nn]);
    *(unsigned*)&Wt[(size_t)(n0 + nn) * 2048 + k0 + c2 * 2] = pk;
  }
}

// ======== 128-row SINGLE-phase/K-tile MFMA GEMM, 2 blocks/CU (R12) ========
// BM=128, BK=64, 8 waves (2M x 4N), wave tile 64 x (BN/4).
// Per K-tile: {stage full next tile -> vmcnt(2+NB) -> bar -> ds_reads + 24
// MFMA (compiler interleaves lgkmcnt) -> bar}. 2 blocks/CU cover the
// stage/barrier segment. LDS: (16 + BN/64*8)KB x2 -> 80KB @192, 64KB @128.
// bid mapping: row-major (R12 best-measured).
// EPI: 0 = fp32 C, 2 = fused qkv epilogue (rope q/k, v->vt^T)
template <int BN, int EPI>
__global__ __launch_bounds__(512, 4) void k_gemm1(const bf16* __restrict__ A,
                                                  const bf16* __restrict__ Bt,
                                                  void* __restrict__ Cout,
                                                  int M, int N, int K,
                                                  const float* __restrict__ cosT,
                                                  const float* __restrict__ sinT,
                                                  bf16* __restrict__ vt) {
  constexpr int NR = BN / 64;          // n-frags per wave (3 or 2)
  constexpr int NB = BN * 128 / 8192;  // B stage-issues per tile (3 or 2)
  __shared__ __align__(16) char As_[2][16384];
  __shared__ __align__(16) char Bs_[2][BN * 128];

  const int tid = threadIdx.x;
  const int w = tid >> 6, lane = tid & 63;
  const int li = lane & 15, g = lane >> 4;
  const int wm = w >> 2, wn = w & 3;

  const int nwg = gridDim.x * gridDim.y;
  int bid = blockIdx.y * gridDim.x + blockIdx.x;
  bid = (bid & 7) * (nwg >> 3) + (bid >> 3);
  const int m0 = (bid / gridDim.x) * 128;
  const int n0 = (bid % gridDim.x) * BN;

  const int ntiles = K >> 6;

  // A half h = rows with bit5==h; within half, rl = (row&31) + 32*(row>>6)
  auto sA = [&](int buf, int tile, int h) {
    if (tile >= ntiles) return;
    const int rl = tid >> 3;              // 0..63
    const int row = (rl & 31) + h * 32 + ((rl >> 5) << 6);
    const int sl = tid & 7;
    const bf16* src = A + (size_t)(m0 + row) * K + tile * 64 + ((sl ^ (rl & 7)) * 8);
    gload_lds16(src, As_[buf] + h * 8192 + tid * 16);
  };
  auto sB = [&](int buf, int tile, int issue) {
    if (tile >= ntiles) return;
    const int block = issue * 8 + w;
    const int rr = block * 8 + (lane >> 3);
    const int sl = lane & 7;
    const bf16* src = Bt + (size_t)(n0 + rr) * K + tile * 64 + ((sl ^ (rr & 7)) * 8);
    gload_lds16(src, Bs_[buf] + block * 1024);
  };

  const int swz0 = (g ^ (li & 7)) * 16;
  const int swz1 = ((4 + g) ^ (li & 7)) * 16;
  bf16x8 af[8], bv[NR * 2];
  f32x4 acc[4][NR] = {};

  auto readA = [&](int buf) {  // 4 m-frags; frag mf row-base = wm*64 + mf*16
#pragma unroll
    for (int mf = 0; mf < 4; ++mf) {
      const int h = (mf >> 1) & 1;
      const int rl = (mf & 1) * 16 + li + 32 * wm;
      const char* p = As_[buf] + h * 8192 + rl * 128;
      af[mf * 2 + 0] = *(const bf16x8*)(p + swz0);
      af[mf * 2 + 1] = *(const bf16x8*)(p + swz1);
    }
  };
  auto readB = [&](int buf) {
#pragma unroll
    for (int n = 0; n < NR; ++n) {
      const char* p = Bs_[buf] + (wn * (NR * 16) + n * 16 + li) * 128;
      bv[n * 2 + 0] = *(const bf16x8*)(p + swz0);
      bv[n * 2 + 1] = *(const bf16x8*)(p + swz1);
    }
  };
  auto MMA = [&]() {
    __builtin_amdgcn_s_setprio(1);
#pragma unroll
    for (int mf = 0; mf < 4; ++mf)
#pragma unroll
      for (int n = 0; n < NR; ++n)
#pragma unroll
        for (int kk = 0; kk < 2; ++kk)
          acc[mf][n] = __builtin_amdgcn_mfma_f32_16x16x32_bf16(
              af[mf * 2 + kk], bv[n * 2 + kk], acc[mf][n], 0, 0, 0);
    __builtin_amdgcn_s_setprio(0);
  };

  // ---- prologue: stage tile0 (2+NB issues) ----
  sA(0, 0, 0); sA(0, 0, 1);
#pragma unroll
  for (int i = 0; i < NB; ++i) sB(0, 0, i);

  for (int t = 0; t < ntiles; ++t) {
    const int cb = t & 1;
    const bool last = (t == ntiles - 1);
    sA(cb ^ 1, t + 1, 0); sA(cb ^ 1, t + 1, 1);
#pragma unroll
    for (int i = 0; i < NB; ++i) sB(cb ^ 1, t + 1, i);
    if (last)
      asm volatile("s_waitcnt vmcnt(0)" ::: "memory");
    else if constexpr (NB == 3)
      asm volatile("s_waitcnt vmcnt(5)" ::: "memory");
    else
      asm volatile("s_waitcnt vmcnt(4)" ::: "memory");
    __builtin_amdgcn_sched_barrier(0);
    FBAR();
    readA(cb); readB(cb);
    MMA();
    FBAR();
  }

  // ---------------- epilogue ----------------
#pragma unroll
  for (int mf = 0; mf < 4; ++mf)
#pragma unroll
    for (int nf = 0; nf < NR; ++nf) {
      const int colc = n0 + wn * (NR * 16) + nf * 16;  // wave-uniform
      const int col = colc + li;
      const int row0 = m0 + wm * 64 + mf * 16 + g * 4;
      if constexpr (EPI == 2) {
        if (colc < QKS) {  // q or k: rope (q additionally pre-scaled)
          const float qs = (colc < 2048) ? 0.08838834764831845f : 1.0f;
          const int i = (col & 127) >> 1;
          const float sgn = (li & 1) ? 1.0f : -1.0f;
#pragma unroll
          for (int r = 0; r < 4; ++r) {
            const int trow = (row0 + r) & (T_ - 1);
            float v = acc[mf][nf][r];
            float pv = __shfl_xor(v, 1);
            float c = cosT[trow * 64 + i], s = sinT[trow * 64 + i];
            float o = (v * c + pv * (sgn * s)) * qs;
            ((bf16*)Cout)[(size_t)(row0 + r) * QKS + col] = __float2bfloat16(o);
          }
        } else {  // v: write transposed into vt[col-2560][row], 4 rows packed
          unsigned lo = pack_bf2(acc[mf][nf][0], acc[mf][nf][1]);
          unsigned hi = pack_bf2(acc[mf][nf][2], acc[mf][nf][3]);
          uint2 pk = {lo, hi};
          *(uint2*)(vt + (size_t)(col - QKS) * (B_ * T_) + row0) = pk;
        }
      } else {
#pragma unroll
        for (int r = 0; r < 4; ++r)
          ((float*)Cout)[(size_t)(row0 + r) * N + col] = acc[mf][nf][r];
      }
    }
}

// ---------------- windowed flash attention, swapped QK^T (R7 config) -------
// grid: (T/32 [reversed], B*NKV), block 512 = 8 waves.
// wave w: head kvh*4 + (w>>1), q rows t0 + (w&1)*16 .. +15. LDS 48KB: 3/CU.
__global__ __launch_bounds__(512) void k_attn(const bf16* __restrict__ qkv,
                                              const bf16* __restrict__ vt,
                                              bf16* __restrict__ Y) {
  __shared__ __align__(16) char Ks[2][9216];
  __shared__ __align__(16) char Vs[2][10240];
  __shared__ __align__(16) char Pl[8][1280];
  const int lane = threadIdx.x & 63;
  const int w = threadIdx.x >> 6;
  const int li = lane & 15, g = lane >> 4;
  const int t0 = ((int)gridDim.x - 1 - (int)blockIdx.x) * 32;
  const int b = blockIdx.y / NKV, kvh = blockIdx.y % NKV;
  const int h = kvh * 4 + (w >> 1);
  const int qrow0 = t0 + (w & 1) * 16;
  const int t = qrow0 + li;

  bf16x8 qf[4];
  const bf16* qbase = qkv + (size_t)(b * T_ + qrow0 + li) * QKS + h * DH;
#pragma unroll
  for (int dk = 0; dk < 4; ++dk) qf[dk] = *(const bf16x8*)(qbase + dk * 32 + g * 8);

  float mrow = -1e4f;
  float srow = 0.f;
  f32x4 acc[8] = {};

  int ks0 = t0 - (WIN - 1);
  if (ks0 < 0) ks0 = 0;
  ks0 &= ~31;
  const int nt = (t0 + 31 - ks0) / 32 + 1;

  const bf16* kgbase = qkv + (size_t)(b * T_) * QKS + DM + kvh * DH;
  const bf16* vgbase = vt + (size_t)(kvh * DH) * (B_ * T_) + b * T_;

  auto STAGE = [&](int buf, int kt) {
    for (int c = w; c < 19; c += 8) {
      if (c < 9) {
        int slot = c * 64 + lane;
        int row = slot / 17, cc = slot % 17;
        if (slot >= 544) { row = 0; cc = 0; }
        if (cc == 16) cc = 0;
        const bf16* src = kgbase + (size_t)(kt + row) * QKS + cc * 8;
        gload_lds16(src, Ks[buf] + c * 1024);
      } else {
        int c2 = c - 9;
        int slot = c2 * 64 + lane;
        int row = slot / 5, cc = slot % 5;
        if (cc == 4) cc = 0;
        const bf16* src = vgbase + (size_t)row * (B_ * T_) + kt + cc * 8;
        gload_lds16(src, Vs[buf] + c2 * 1024);
      }
    }
  };

  STAGE(0, ks0);
  __syncthreads();
  int cur = 0;

  for (int it = 0; it < nt; ++it) {
    const int kt = ks0 + it * 32;
    if (it + 1 < nt) STAGE(cur ^ 1, kt + 32);

    f32x4 sc[2] = {};
#pragma unroll
    for (int n = 0; n < 2; ++n)
#pragma unroll
      for (int dk = 0; dk < 4; ++dk) {
        bf16x8 kf = *(const bf16x8*)(Ks[cur] + (n * 16 + li) * 272 + dk * 64 + g * 16);
        sc[n] = __builtin_amdgcn_mfma_f32_16x16x32_bf16(kf, qf[dk], sc[n], 0, 0, 0);
      }

    float p[2][4];
    float pmax = -1e30f;
#pragma unroll
    for (int n = 0; n < 2; ++n)
#pragma unroll
      for (int r = 0; r < 4; ++r) {
        int key = kt + n * 16 + g * 4 + r;
        bool valid = (key <= t) && (key > t - WIN);
        float pv = valid ? sc[n][r] : -1e30f;
        p[n][r] = pv;
        pmax = fmaxf(pmax, pv);
      }
    pmax = fmaxf(pmax, __shfl_xor(pmax, 16));
    pmax = fmaxf(pmax, __shfl_xor(pmax, 32));

    // T13 defer-rescale: only rescale when the running max actually grows
    if (!__all(pmax <= mrow)) {
      float nm = fmaxf(mrow, pmax);
      float alpha = __expf(mrow - nm);
      mrow = nm;
      srow *= alpha;
      float af_[4];
#pragma unroll
      for (int r = 0; r < 4; ++r) af_[r] = __shfl(alpha, (g << 2) + r);
#pragma unroll
      for (int db = 0; db < 8; ++db)
#pragma unroll
        for (int r = 0; r < 4; ++r) acc[db][r] *= af_[r];
    }

    float rs = 0.f;
#pragma unroll
    for (int n = 0; n < 2; ++n)
#pragma unroll
      for (int r = 0; r < 4; ++r) {
        p[n][r] = __expf(p[n][r] - mrow);
        rs += p[n][r];
      }
    rs += __shfl_xor(rs, 16);
    rs += __shfl_xor(rs, 32);
    srow += rs;

#pragma unroll
    for (int n = 0; n < 2; ++n) {
      *(unsigned*)(Pl[w] + li * 80 + n * 32 + g * 8) = pack_bf2(p[n][0], p[n][1]);
      *(unsigned*)(Pl[w] + li * 80 + n * 32 + g * 8 + 4) = pack_bf2(p[n][2], p[n][3]);
    }

    bf16x8 pf = *(const bf16x8*)(Pl[w] + li * 80 + g * 16);
#pragma unroll
    for (int db = 0; db < 8; ++db) {
      bf16x8 vf = *(const bf16x8*)(Vs[cur] + (db * 16 + li) * 80 + g * 16);
      acc[db] = __builtin_amdgcn_mfma_f32_16x16x32_bf16(pf, vf, acc[db], 0, 0, 0);
    }

    __syncthreads();
    cur ^= 1;
  }

  float inv[4];
#pragma unroll
  for (int r = 0; r < 4; ++r) inv[r] = 1.f / __shfl(srow, (g << 2) + r);
  bf16* ybase = Y + (size_t)(b * T_ + qrow0 + (g << 2)) * DM + h * DH;
#pragma unroll
  for (int r = 0; r < 4; ++r)
#pragma unroll
    for (int db = 0; db < 8; ++db)
      ybase[(size_t)r * DM + db * 16 + li] = __float2bfloat16(acc[db][r] * inv[r]);
}

extern "C" void kernel_launch(void* const* d_in, const int* in_sizes, int n_in,
                              void* d_out, int out_size, void* d_ws, size_t ws_size,
                              hipStream_t stream) {
  const float* x = (const float*)d_in[0];
  const float* cosT = (const float*)d_in[1];
  const float* sinT = (const float*)d_in[2];
  const float* Wq = (const float*)d_in[3];
  const float* Wk = (const float*)d_in[4];
  const float* Wv = (const float*)d_in[5];
  const float* Wo = (const float*)d_in[6];
  float* out = (float*)d_out;

  char* ws = (char*)d_ws;
  bf16* xb = (bf16*)ws;     ws += (size_t)4096 * 2048 * 2;   // 16.8 MB (reused as yb)
  bf16* Wqkvt = (bf16*)ws;  ws += (size_t)3072 * 2048 * 2;   // 12.6 MB
  bf16* Wot = (bf16*)ws;    ws += (size_t)2048 * 2048 * 2;   // 8.4 MB
  bf16* qkv = (bf16*)ws;    ws += (size_t)4096 * QKS * 2;    // 21.0 MB (q|k only)
  bf16* vt = (bf16*)ws;     ws += (size_t)512 * 4096 * 2;    // 4.2 MB (V^T)
  bf16* yb = xb;

  k_prep<<<4608, 256, 0, stream>>>(x, Wq, Wk, Wv, Wo, xb, Wqkvt, Wot);

  k_gemm1<192, 2><<<dim3(3072 / 192, 4096 / 128), 512, 0, stream>>>(
      xb, Wqkvt, qkv, 4096, 3072, 2048, cosT, sinT, vt);

  k_attn<<<dim3(T_ / 32, B_ * NKV), 512, 0, stream>>>(qkv, vt, yb);

  k_gemm1<128, 0><<<dim3(2048 / 128, 4096 / 128), 512, 0, stream>>>(
      yb, Wot, out, 4096, 2048, 2048, nullptr, nullptr, nullptr);
}